// Round 1
// 297.009 us; speedup vs baseline: 1.1101x; 1.1101x over previous
//
#include <hip/hip_runtime.h>

// CosformerAttention on MI355X (gfx950). Inputs fp32, OUTPUT fp32.
// B=8, E=768, L=48*48=2304, heads=12, d=64, n=B*h=96, M=L*B=18432.
//
// Round-8: both dense GEMMs (QKV projection + output projection) rewritten
// from the 128^2/BK=32 2-barrier structure (ceiling'd at ~580 TF here,
// MfmaUtil 24.5%) to the verified 256^2 8-phase template:
//   T2 LDS XOR-swizzle (pre-swizzled global source + swizzled ds_read),
//   T3/T4 8-phase interleave with counted vmcnt(4) (never drain-0 in loop),
//   T5 s_setprio around MFMA clusters, raw s_barrier (no vmcnt0 drain),
//   bijective XCD-chunked block swizzle (each XCD owns disjoint A panels).
// kv_mfma / attn_mfma / conv_w / transpose_q unchanged from round-7.

#define L_SEQ 2304
#define BATCH 8
#define EDIM 768
#define NHEAD 12
#define DHEAD 64
#define MROWS (L_SEQ * BATCH)  // 18432

typedef __attribute__((ext_vector_type(8))) short bf16x8_t;   // 8 bf16 = 4 VGPRs
typedef __attribute__((ext_vector_type(4))) float f32x4_t;

__device__ __forceinline__ float b2f(unsigned short u) {
  union { unsigned int i; float f; } x; x.i = ((unsigned int)u) << 16; return x.f;
}
__device__ __forceinline__ unsigned short f2b(float f) {
  union { float f; unsigned int i; } x; x.f = f;
  unsigned int r = x.i + 0x7FFFu + ((x.i >> 16) & 1u);  // RNE
  return (unsigned short)(r >> 16);
}

// async 16B global->LDS (gfx950; wave-uniform base + lane*16 dest contract)
#define GLOAD_LDS16(g, l)                                                     \
  __builtin_amdgcn_global_load_lds(                                           \
      (const __attribute__((address_space(1))) unsigned int*)(g),             \
      (__attribute__((address_space(3))) unsigned int*)(l), 16, 0, 0)

// ---------------------------------------------------------------------------
// Kernel 0: convert 4 fp32 weight matrices (768x768) to bf16.
__global__ __launch_bounds__(256) void conv_w(
    const float* __restrict__ W0, const float* __restrict__ W1,
    const float* __restrict__ W2, const float* __restrict__ W3,
    unsigned short* __restrict__ dst) {
  const float* W = (blockIdx.y == 0) ? W0 : (blockIdx.y == 1) ? W1
                 : (blockIdx.y == 2) ? W2 : W3;
  unsigned short* d = dst + (size_t)blockIdx.y * EDIM * EDIM;
  int idx = blockIdx.x * 256 + threadIdx.x;  // [0, 147456)
  float4 v = *(const float4*)(W + (size_t)idx * 4);
  ushort4 o;
  o.x = f2b(v.x); o.y = f2b(v.y); o.z = f2b(v.z); o.w = f2b(v.w);
  *(ushort4*)(d + (size_t)idx * 4) = o;
}

// ---------------------------------------------------------------------------
// Kernel 1: transpose query (B, E, L) fp32 -> xT (B*L, E) bf16.
__global__ __launch_bounds__(256) void transpose_q(
    const float* __restrict__ q, unsigned short* __restrict__ xT) {
  __shared__ float tile[64][65];
  int b = blockIdx.z;
  int e0 = blockIdx.x * 64;
  int l0 = blockIdx.y * 64;
  int t = threadIdx.x;
  int li = t & 63, er = t >> 6;
#pragma unroll
  for (int p = 0; p < 16; p++) {
    int eo = er + p * 4;
    tile[eo][li] = q[((size_t)b * EDIM + (e0 + eo)) * L_SEQ + (l0 + li)];
  }
  __syncthreads();
  int ei = t & 63, lr = t >> 6;
#pragma unroll
  for (int p = 0; p < 16; p++) {
    int lo = lr + p * 4;
    xT[((size_t)b * L_SEQ + (l0 + lo)) * EDIM + (e0 + ei)] = f2b(tile[ei][lo]);
  }
}

// ---------------------------------------------------------------------------
// Kernel 2/5: C = A @ W^T (+bias, opt relu). 256x256 tile, BK=64, 512 thr
// (8 waves, 2Mx4N), 8-phase pipelined K-loop, 128 KiB dynamic LDS.
//
// LDS map (ushort elems): A(buf,half) = buf*16384 + half*8192
//                         B(buf,half) = 32768 + buf*16384 + half*8192
// Each half = 128 rows x 64 cols bf16, XOR-swizzled: elem = r*64 + (k ^ ((r&7)<<3)).
// Stage writes are linear (global_load_lds contract) with the inverse swizzle
// applied to the global SOURCE column; ds_read applies the same XOR.
//
// Schedule (iteration i computes kt0=2i from buf0, kt1=2i+1 from buf1;
// one half-tile staged per phase; regions staged are >=2 barriers past
// their last reader; vmcnt(4) at ph4/ph8 guards all reads one K-tile out):
//  ph1: rd A0B0(buf0), stg A1(kt1)->buf1      ph5: rd A0B0(buf1), stg A1(kt0+2)->buf0
//  ph2: rd B1(buf0),   stg B1(kt1)->buf1      ph6: rd B1(buf1),   stg B1(kt0+2)->buf0
//  ph3: rd A1(buf0),   stg A0(kt0+2)->buf0    ph7: rd A1(buf1),   stg A0(kt1+2)->buf1
//  ph4: (no rd),       stg B0(kt0+2)->buf0,   ph8: (no rd),       stg B0(kt1+2)->buf1,
//       vmcnt(4)                                   vmcnt(4)
#define ALDSO(b_, h_) ((b_) * 16384 + (h_) * 8192)
#define BLDSO(b_, h_) (32768 + (b_) * 16384 + (h_) * 8192)

#define BARF()                                  \
  {                                             \
    asm volatile("" ::: "memory");              \
    __builtin_amdgcn_s_barrier();               \
    asm volatile("" ::: "memory");              \
    __builtin_amdgcn_sched_barrier(0);          \
  }
#define WAITL()                                              \
  {                                                          \
    asm volatile("s_waitcnt lgkmcnt(0)" ::: "memory");       \
    __builtin_amdgcn_sched_barrier(0);                       \
  }
#define VMW(N) asm volatile("s_waitcnt vmcnt(" #N ")" ::: "memory")

#define STG_A(h_, kt_, LB_)                                                          \
  {                                                                                  \
    GLOAD_LDS16(a_sb + (size_t)((h_) * 128) * EDIM + (kt_) * 64, lds + (LB_) + t * 8); \
    GLOAD_LDS16(a_sb + (size_t)((h_) * 128 + 64) * EDIM + (kt_) * 64,                \
                lds + (LB_) + 4096 + t * 8);                                         \
  }
#define STG_B(h_, kt_, LB_)                                                          \
  {                                                                                  \
    GLOAD_LDS16(b_sb + (size_t)((h_) * 128) * EDIM + (kt_) * 64, lds + (LB_) + t * 8); \
    GLOAD_LDS16(b_sb + (size_t)((h_) * 128 + 64) * EDIM + (kt_) * 64,                \
                lds + (LB_) + 4096 + t * 8);                                         \
  }

#define DS_A(SET, B_, H_)                                                            \
  _Pragma("unroll") for (int i_ = 0; i_ < 4; i_++)                                   \
  _Pragma("unroll") for (int kk_ = 0; kk_ < 2; kk_++)                                \
    SET[i_][kk_] = *(const bf16x8_t*)(lds + ALDSO(B_, H_) +                          \
                                      ((a_base + i_ * 1024 + kk_ * 32) ^ xorv));

#define DS_B(SET, B_, H_)                                                            \
  _Pragma("unroll") for (int j_ = 0; j_ < 2; j_++)                                   \
  _Pragma("unroll") for (int kk_ = 0; kk_ < 2; kk_++)                                \
    SET[j_][kk_] = *(const bf16x8_t*)(lds + BLDSO(B_, H_) +                          \
                                      ((b_base + j_ * 1024 + kk_ * 32) ^ xorv));

#define MFMAQ(ASET, BSET, AH, BH)                                                    \
  __builtin_amdgcn_s_setprio(1);                                                     \
  _Pragma("unroll") for (int i_ = 0; i_ < 4; i_++)                                   \
  _Pragma("unroll") for (int j_ = 0; j_ < 2; j_++)                                   \
  _Pragma("unroll") for (int kk_ = 0; kk_ < 2; kk_++)                                \
    acc[(AH) * 4 + i_][(BH) * 2 + j_] = __builtin_amdgcn_mfma_f32_16x16x32_bf16(     \
        ASET[i_][kk_], BSET[j_][kk_], acc[(AH) * 4 + i_][(BH) * 2 + j_], 0, 0, 0);   \
  __builtin_amdgcn_s_setprio(0);

template <int MODE>
__global__ __launch_bounds__(512, 2) void gemm256(
    const unsigned short* __restrict__ A,
    const unsigned short* __restrict__ Wall,
    const float* __restrict__ bias0, const float* __restrict__ bias1,
    const float* __restrict__ bias2,
    unsigned short* __restrict__ dst0, unsigned short* __restrict__ dst1,
    unsigned short* __restrict__ dst2,
    float* __restrict__ dstf) {
  extern __shared__ __align__(16) unsigned short lds[];

  // --- block decode with bijective XCD-chunked swizzle (nwg % 8 == 0) ---
  const unsigned short* W;
  const float* bias;
  unsigned short* dst = nullptr;
  bool do_relu = false;
  int rowblk, colblk;
  {
    int nwg = (int)gridDim.x;
    int wg = ((int)blockIdx.x & 7) * (nwg >> 3) + ((int)blockIdx.x >> 3);
    if (MODE == 0) {
      rowblk = wg / 9;                 // 72 row panels; each XCD gets 9 disjoint
      int c = wg - rowblk * 9;
      colblk = c % 3;
      int z = c / 3;
      W = Wall + (size_t)z * EDIM * EDIM;
      bias = (z == 0) ? bias0 : (z == 1) ? bias1 : bias2;
      dst = (z == 0) ? dst0 : (z == 1) ? dst1 : dst2;
      do_relu = (z < 2);
    } else {
      rowblk = wg / 3;
      colblk = wg - rowblk * 3;
      W = Wall;
      bias = bias0;
    }
  }
  const int row0 = rowblk * 256;
  const int col0 = colblk * 256;

  const int t = threadIdx.x;
  const int lane = t & 63;
  const int wave = t >> 6;
  const int wm = wave >> 2;      // 0..1 (M split)
  const int wn = wave & 3;       // 0..3 (N split)
  const int mrow = lane & 15;
  const int quad = lane >> 4;

  // ds_read addressing (elements within a 128x64 half; XOR is per-thread const)
  const int xorv = (mrow & 7) << 3;
  const int a_base = (wm * 64 + mrow) * 64 + quad * 8;
  const int b_base = (wn * 32 + mrow) * 64 + quad * 8;

  // stage addressing: thread t covers LDS bytes [t*16) -> row lr_s = t>>3,
  // source col pre-swizzled so the linear DMA write lands swizzled data.
  const int lr_s = t >> 3;                              // 0..63
  const int k0_s = ((((t >> 3) & 7) ^ (t & 7)) << 3);   // 0..56
  const unsigned short* a_sb = A + (size_t)(row0 + lr_s) * EDIM + k0_s;
  const unsigned short* b_sb = W + (size_t)(col0 + lr_s) * EDIM + k0_s;

  f32x4_t acc[8][4] = {};
  bf16x8_t aA[4][2], aB[4][2], bA[2][2], bB[2][2];

  // --- prologue: buf0 <- kt0, buf1 <- A0/B0 of kt1; vmcnt(4) => buf0 landed ---
  STG_A(0, 0, ALDSO(0, 0));
  STG_B(0, 0, BLDSO(0, 0));
  STG_A(1, 0, ALDSO(0, 1));
  STG_B(1, 0, BLDSO(0, 1));
  STG_A(0, 1, ALDSO(1, 0));
  STG_B(0, 1, BLDSO(1, 0));
  VMW(4);
  BARF();

#pragma unroll
  for (int i = 0; i < 6; ++i) {      // K = 768 = 6 iters x 2 K-tiles x BK=64
    const int kt0 = 2 * i, kt1 = 2 * i + 1;
    const bool nxt = (i < 5);
    // ph1
    DS_A(aA, 0, 0);
    DS_B(bA, 0, 0);
    STG_A(1, kt1, ALDSO(1, 1));
    BARF();
    WAITL();
    MFMAQ(aA, bA, 0, 0);
    BARF();
    // ph2
    DS_B(bB, 0, 1);
    STG_B(1, kt1, BLDSO(1, 1));
    BARF();
    WAITL();
    MFMAQ(aA, bB, 0, 1);
    BARF();
    // ph3
    DS_A(aB, 0, 1);
    if (nxt) STG_A(0, kt0 + 2, ALDSO(0, 0));
    BARF();
    WAITL();
    MFMAQ(aB, bA, 1, 0);
    BARF();
    // ph4
    if (nxt) STG_B(0, kt0 + 2, BLDSO(0, 0));
    BARF();
    MFMAQ(aB, bB, 1, 1);
    if (nxt) { VMW(4); } else { VMW(0); }
    BARF();
    // ph5
    DS_A(aA, 1, 0);
    DS_B(bA, 1, 0);
    if (nxt) STG_A(1, kt0 + 2, ALDSO(0, 1));
    BARF();
    WAITL();
    MFMAQ(aA, bA, 0, 0);
    BARF();
    // ph6
    DS_B(bB, 1, 1);
    if (nxt) STG_B(1, kt0 + 2, BLDSO(0, 1));
    BARF();
    WAITL();
    MFMAQ(aA, bB, 0, 1);
    BARF();
    // ph7
    DS_A(aB, 1, 1);
    if (nxt) STG_A(0, kt1 + 2, ALDSO(1, 0));
    BARF();
    WAITL();
    MFMAQ(aB, bA, 1, 0);
    BARF();
    // ph8
    if (nxt) STG_B(0, kt1 + 2, BLDSO(1, 0));
    BARF();
    MFMAQ(aB, bB, 1, 1);
    if (nxt) { VMW(4); } else { VMW(0); }
    BARF();
  }

  // --- epilogue ---
  // wave (wm,wn): rows = {row0 + h*128 + wm*64 + i*16}, cols = {col0 + h*128 + wn*32 + j*16}
  // D frag: col = mrow, row = quad*4 + r.
  const int bb = row0 / L_SEQ;  // valid for MODE 0 (2304 = 9*256)
#pragma unroll
  for (int ti = 0; ti < 8; ti++) {
    int rbase = row0 + (ti >> 2) * 128 + wm * 64 + (ti & 3) * 16 + quad * 4;
#pragma unroll
    for (int tj = 0; tj < 4; tj++) {
      int gc = col0 + (tj >> 1) * 128 + wn * 32 + (tj & 1) * 16 + mrow;
      float bv = bias[gc];
#pragma unroll
      for (int r = 0; r < 4; r++) {
        int gr = rbase + r;
        float v = acc[ti][tj][r] + bv;
        if (MODE == 0) {
          if (do_relu) v = fmaxf(v, 0.0f);
          int ll = gr - bb * L_SEQ;
          int n = bb * NHEAD + (gc >> 6);
          dst[((size_t)n * L_SEQ + ll) * DHEAD + (gc & 63)] = f2b(v);
        } else {
          dstf[(size_t)gr * EDIM + gc] = v;  // FP32 output
        }
      }
    }
  }
}

// ---------------------------------------------------------------------------
// Kernel 3 (MFMA): kv[n][j][m] = sum_l k_[l][j]*v[l][m], ksum[n][j] = sum_l k_.
__global__ __launch_bounds__(256) void kv_mfma(
    const unsigned short* __restrict__ kbuf, const unsigned short* __restrict__ vbuf,
    float* __restrict__ kv, float* __restrict__ ksum) {
  constexpr int ST = 40;  // LDS row stride (bf16)
  __shared__ __align__(16) unsigned short ksT[128 * ST];
  __shared__ __align__(16) unsigned short vsT[80 * ST];
  int n = blockIdx.x;
  int lbase = blockIdx.y * 288;
  int t = threadIdx.x;
  int lane = t & 63, wave = t >> 6;
  int mrow = lane & 15, quad = lane >> 4;

  for (int i = t; i < 16 * ST; i += 256) {
    int row = i / ST, col = i % ST;
    vsT[(64 + row) * ST + col] = (row == 0 && col < 32) ? (unsigned short)0x3F80 : 0;
  }

  int lrd = t >> 3;
  int oct = t & 7;
  const unsigned short* kbase = kbuf + (size_t)n * L_SEQ * DHEAD + oct * 8;
  const unsigned short* vbase = vbuf + (size_t)n * L_SEQ * DHEAD + oct * 8;

  f32x4_t acc[2][5] = {};

  for (int s = 0; s < 9; s++) {
    int l = lbase + s * 32 + lrd;
    float sv, cv;
    sincosf(1.5707963267948966f * (float)(l + 1) / 2304.0f, &sv, &cv);
    union { uint4 q; unsigned short u[8]; } kq, vq;
    kq.q = *(const uint4*)(kbase + (size_t)l * DHEAD);
    vq.q = *(const uint4*)(vbase + (size_t)l * DHEAD);
    __syncthreads();
#pragma unroll
    for (int e = 0; e < 8; e++) {
      int d = oct * 8 + e;
      float kval = b2f(kq.u[e]);
      ksT[d * ST + lrd] = f2b(kval * sv);
      ksT[(64 + d) * ST + lrd] = f2b(kval * cv);
      vsT[d * ST + lrd] = vq.u[e];
    }
    __syncthreads();
    bf16x8_t af[2];
#pragma unroll
    for (int ti = 0; ti < 2; ti++)
      af[ti] = *(const bf16x8_t*)(ksT + ((wave * 2 + ti) * 16 + mrow) * ST + quad * 8);
#pragma unroll
    for (int tj = 0; tj < 5; tj++) {
      bf16x8_t bfv = *(const bf16x8_t*)(vsT + (tj * 16 + mrow) * ST + quad * 8);
#pragma unroll
      for (int ti = 0; ti < 2; ti++)
        acc[ti][tj] = __builtin_amdgcn_mfma_f32_16x16x32_bf16(af[ti], bfv, acc[ti][tj], 0, 0, 0);
    }
  }

#pragma unroll
  for (int ti = 0; ti < 2; ti++) {
#pragma unroll
    for (int r = 0; r < 4; r++) {
      int j = (wave * 2 + ti) * 16 + quad * 4 + r;
#pragma unroll
      for (int tj = 0; tj < 4; tj++) {
        int m = tj * 16 + mrow;
        atomicAdd(&kv[((size_t)n * 128 + j) * 64 + m], acc[ti][tj][r]);
      }
      if (mrow == 0) atomicAdd(&ksum[n * 128 + j], acc[ti][4][r]);
    }
  }
}

// ---------------------------------------------------------------------------
// Kernel 4 (MFMA): C0 = q@kv0, C1 = q@kv1; out = zs*C0 + zc*C1; fused
// residual + relayout. grid (18, 96), block 256.
__global__ __launch_bounds__(256) void attn_mfma(
    const unsigned short* __restrict__ qbuf, const float* __restrict__ kv,
    const float* __restrict__ ksum, const unsigned short* __restrict__ xT,
    unsigned short* __restrict__ attn) {
  __shared__ __align__(16) unsigned short As[128 * 72];
  __shared__ __align__(16) unsigned short Bs[64 * 136];
  __shared__ float ks_l[128];
  __shared__ float zs[128], zc[128];
  int l0 = blockIdx.x * 128;
  int n = blockIdx.y;
  int t = threadIdx.x;
  int lane = t & 63, wave = t >> 6;
  int mrow = lane & 15, quad = lane >> 4;
  int b = n / NHEAD, hd = n % NHEAD;

  {
    int row = t >> 1, off = (t & 1) * 32;
    const unsigned short* src = qbuf + ((size_t)n * L_SEQ + l0 + row) * DHEAD + off;
    unsigned short* d = As + row * 72 + off;
#pragma unroll
    for (int c = 0; c < 4; c++)
      *(uint4*)(d + c * 8) = *(const uint4*)(src + c * 8);
  }
  {
    int j = t >> 1, mh = (t & 1) * 32;
    const float* src = kv + ((size_t)n * 128 + j) * 64 + mh;
#pragma unroll
    for (int mm = 0; mm < 32; mm++)
      Bs[(mh + mm) * 136 + j] = f2b(src[mm]);
  }
  if (t < 128) ks_l[t] = ksum[n * 128 + t];
  __syncthreads();

  if (t < 128) {
    float d0 = 0.f, d1 = 0.f;
    const unsigned short* arow = As + t * 72;
#pragma unroll
    for (int j = 0; j < 8; j++) {
      bf16x8_t v = *(const bf16x8_t*)(arow + j * 8);
#pragma unroll
      for (int e = 0; e < 8; e++) {
        float qv = b2f((unsigned short)v[e]);
        d0 += qv * ks_l[j * 8 + e];
        d1 += qv * ks_l[64 + j * 8 + e];
      }
    }
    float sv, cv;
    sincosf(1.5707963267948966f * (float)(l0 + t + 1) / 2304.0f, &sv, &cv);
    float z = 1.0f / fmaxf(sv * d0 + cv * d1, 1e-6f);
    zs[t] = z * sv;
    zc[t] = z * cv;
  }
  __syncthreads();

  int wr = wave * 32;
  f32x4_t acc0[2][4] = {}, acc1[2][4] = {};
#pragma unroll
  for (int ks = 0; ks < 2; ks++) {
    bf16x8_t af[2];
#pragma unroll
    for (int ti = 0; ti < 2; ti++)
      af[ti] = *(const bf16x8_t*)(As + (wr + ti * 16 + mrow) * 72 + ks * 32 + quad * 8);
#pragma unroll
    for (int tj = 0; tj < 4; tj++) {
      bf16x8_t b0 = *(const bf16x8_t*)(Bs + (tj * 16 + mrow) * 136 + ks * 32 + quad * 8);
      bf16x8_t b1 = *(const bf16x8_t*)(Bs + (tj * 16 + mrow) * 136 + 64 + ks * 32 + quad * 8);
#pragma unroll
      for (int ti = 0; ti < 2; ti++) {
        acc0[ti][tj] = __builtin_amdgcn_mfma_f32_16x16x32_bf16(af[ti], b0, acc0[ti][tj], 0, 0, 0);
        acc1[ti][tj] = __builtin_amdgcn_mfma_f32_16x16x32_bf16(af[ti], b1, acc1[ti][tj], 0, 0, 0);
      }
    }
  }

#pragma unroll
  for (int ti = 0; ti < 2; ti++) {
#pragma unroll
    for (int tj = 0; tj < 4; tj++) {
      int m = tj * 16 + mrow;
#pragma unroll
      for (int r = 0; r < 4; r++) {
        int row = wr + ti * 16 + quad * 4 + r;
        int l = l0 + row;
        float ov = zs[row] * acc0[ti][tj][r] + zc[row] * acc1[ti][tj][r];
        float xv = b2f(xT[((size_t)b * L_SEQ + l) * EDIM + hd * DHEAD + m]);
        attn[((size_t)l * BATCH + b) * EDIM + hd * DHEAD + m] = f2b(xv + ov);
      }
    }
  }
}

// ---------------------------------------------------------------------------
extern "C" void kernel_launch(void* const* d_in, const int* in_sizes, int n_in,
                              void* d_out, int out_size, void* d_ws, size_t ws_size,
                              hipStream_t stream) {
  const float* query = (const float*)d_in[0];
  const float* Wq = (const float*)d_in[1];
  const float* bq = (const float*)d_in[2];
  const float* Wk = (const float*)d_in[3];
  const float* bk = (const float*)d_in[4];
  const float* Wv = (const float*)d_in[5];
  const float* bv = (const float*)d_in[6];
  const float* Wo = (const float*)d_in[7];
  const float* bo = (const float*)d_in[8];
  float* out = (float*)d_out;  // fp32 output

  unsigned short* xT = (unsigned short*)d_out;  // bf16 staging inside d_out

  char* ws = (char*)d_ws;
  const size_t SZ = (size_t)MROWS * EDIM * 2;  // 28,311,552
  unsigned short* qbuf = (unsigned short*)(ws);
  unsigned short* kbuf = (unsigned short*)(ws + SZ);
  unsigned short* vbuf = (unsigned short*)(ws + 2 * SZ);
  unsigned short* attn = kbuf;  // kbuf dead after kv_mfma
  float* kv   = (float*)(ws + 3 * SZ);                    // 3,145,728 B
  float* ksum = (float*)(ws + 3 * SZ + 3145728);          // 49,152 B
  unsigned short* wbf = (unsigned short*)(ws + 3 * SZ + 3145728 + 49152);
  // total ws: 92,848,128 B

  static bool attr_done = false;
  if (!attr_done) {
    (void)hipFuncSetAttribute((const void*)gemm256<0>,
                              hipFuncAttributeMaxDynamicSharedMemorySize, 131072);
    (void)hipFuncSetAttribute((const void*)gemm256<1>,
                              hipFuncAttributeMaxDynamicSharedMemorySize, 131072);
    attr_done = true;
  }

  conv_w<<<dim3(576, 4), 256, 0, stream>>>(Wq, Wk, Wv, Wo, wbf);

  transpose_q<<<dim3(12, 36, 8), 256, 0, stream>>>(query, xT);

  // QKV projection: 72 row panels x 3 col panels x 3 matrices = 648 blocks
  gemm256<0><<<dim3(648), dim3(512), 131072, stream>>>(
      xT, wbf, bq, bk, bv, qbuf, kbuf, vbuf, nullptr);

  hipMemsetAsync(ws + 3 * SZ, 0, 3145728 + 49152, stream);

  kv_mfma<<<dim3(96, 8), 256, 0, stream>>>(kbuf, vbuf, kv, ksum);

  attn_mfma<<<dim3(L_SEQ / 128, 96), 256, 0, stream>>>(qbuf, kv, ksum, xT, attn);

  // output projection: 72 x 3 = 216 blocks
  gemm256<1><<<dim3(216), dim3(512), 131072, stream>>>(
      attn, wbf + 3 * (size_t)EDIM * EDIM, bo, nullptr, nullptr,
      nullptr, nullptr, nullptr, out);
}